// Round 1
// baseline (134.867 us; speedup 1.0000x reference)
//
#include <hip/hip_runtime.h>

typedef __attribute__((ext_vector_type(8))) short short8;
typedef __attribute__((ext_vector_type(4))) float f32x4;

#define KPAD 40   // padded bf16 K-chunk row: 32 data + 8 pad (80B stride, bank-friendly)

// workspace layout (bytes)
#define WS_HID    0u                 // 256*256 f32
#define WS_E      262144u            // 131072 f32
#define WS_CTX    786432u            // 8*256*256 f32
#define WS_GATES  2883584u           // 256*1024 f32
#define WS_WBF    3932160u           // 8*256*40 bf16
#define WS_WCAT   4096000u           // 20*1024*40 bf16
#define WS_X      5734400u           // 20*256*40 bf16  (total 6,144,000 B)

__device__ __forceinline__ unsigned f2bfu(float f) {
    union { float f; unsigned u; } v; v.f = f;
    return (v.u + 0x7FFFu + ((v.u >> 16) & 1u)) >> 16;   // RNE
}
__device__ __forceinline__ float tanh_fast(float x) {
    float e2 = __expf(2.f * x);
    return 1.f - 2.f * __builtin_amdgcn_rcpf(e2 + 1.f);
}
__device__ __forceinline__ float sigmoid_fast(float x) {
    return __builtin_amdgcn_rcpf(1.f + __expf(-x));
}

// ---------------- K0: hid GEMV + weight bf16 pre-chunking ----------------
__global__ __launch_bounds__(256) void k_prep(
    const float* __restrict__ prev_h, const float* __restrict__ W_i2h,
    const float* __restrict__ W_h2h, const float* __restrict__ b_h2h,
    const float* __restrict__ W_ih,  const float* __restrict__ W_hh,
    float* __restrict__ hid, short* __restrict__ Wbf, short* __restrict__ Wcat)
{
    int bid = blockIdx.x, tid = threadIdx.x;
    if (bid < 256) {                       // hid[b][h] = prev_h[b]·W_h2h[h] + b_h2h[h]
        __shared__ float ph[256];
        ph[tid] = prev_h[bid * 256 + tid];
        __syncthreads();
        float acc = b_h2h[tid];
        const float4* w = (const float4*)(W_h2h + tid * 256);
        #pragma unroll 8
        for (int k4 = 0; k4 < 64; ++k4) {
            float4 ww = w[k4];
            acc += ww.x * ph[k4*4+0] + ww.y * ph[k4*4+1] + ww.z * ph[k4*4+2] + ww.w * ph[k4*4+3];
        }
        hid[bid * 256 + tid] = acc;
    } else if (bid < 576) {                // W_i2h -> bf16 chunks [8][256][40]
        int idx = (bid - 256) * 256 + tid;         // < 81920
        int kc = idx / (256 * KPAD);
        int rem = idx % (256 * KPAD);
        int n = rem / KPAD, kk = rem % KPAD;
        float v = (kk < 32) ? W_i2h[n * 256 + kc * 32 + kk] : 0.f;
        Wbf[idx] = (short)f2bfu(v);
    } else {                               // [W_ih | W_hh] -> bf16 chunks [20][1024][40]
        int idx = (bid - 576) * 256 + tid;         // < 819200
        int kc = idx / (1024 * KPAD);
        int rem = idx % (1024 * KPAD);
        int n = rem / KPAD, kk = rem % KPAD;
        float v = 0.f;
        if (kk < 32) {
            int k = kc * 32 + kk;
            if (k < 352)      v = W_ih[n * 352 + k];
            else if (k < 608) v = W_hh[n * 256 + (k - 352)];
        }
        Wcat[idx] = (short)f2bfu(v);
    }
}

// ---------------- K1: e[bt] = sum_h Wsc[h]*tanh(BH·W_i2h^T + hid) ----------------
// block: 64 bt-rows x 256 h-cols, 4 waves (N-split 4x64), K=256 in 8 steps of 32
__global__ __launch_bounds__(256, 3) void k_escore(
    const float* __restrict__ BH, const short* __restrict__ Wbf,
    const float* __restrict__ hid, const float* __restrict__ Wsc,
    float* __restrict__ e_out)
{
    __shared__ short Al[2][64 * KPAD];
    __shared__ short Bl[2][256 * KPAD];
    __shared__ float eps[4][64];

    const int tid = threadIdx.x;
    const int lane = tid & 63;
    const int w = tid >> 6;
    const int l15 = lane & 15, lg = lane >> 4;
    const int bt0 = blockIdx.x * 64;
    const int b = bt0 >> 9;

    const int arow = tid >> 2, akg = tid & 3;
    const float* asrc = BH + (size_t)(bt0 + arow) * 256 + akg * 8;

    f32x4 acc[4][4];
    #pragma unroll
    for (int i = 0; i < 4; i++)
        #pragma unroll
        for (int j = 0; j < 4; j++) acc[i][j] = (f32x4){0.f, 0.f, 0.f, 0.f};

    auto stage = [&](int kc, int bu) {
        // A: 64x32 fp32 -> bf16 (each thread: 8 floats of one row)
        float4 x0 = *(const float4*)(asrc + kc * 32);
        float4 x1 = *(const float4*)(asrc + kc * 32 + 4);
        int4 p;
        p.x = (int)((f2bfu(x0.y) << 16) | f2bfu(x0.x));
        p.y = (int)((f2bfu(x0.w) << 16) | f2bfu(x0.z));
        p.z = (int)((f2bfu(x1.y) << 16) | f2bfu(x1.x));
        p.w = (int)((f2bfu(x1.w) << 16) | f2bfu(x1.z));
        *(int4*)&Al[bu][arow * KPAD + akg * 8] = p;
        // B: pre-chunked bf16 [kc][256][40]; thread = one n-row (80B = 5x int4)
        const int4* bs = (const int4*)(Wbf + (size_t)(kc * 256 + tid) * KPAD);
        int4* bd = (int4*)&Bl[bu][tid * KPAD];
        #pragma unroll
        for (int i = 0; i < 5; i++) bd[i] = bs[i];
    };

    stage(0, 0);
    __syncthreads();

    for (int ks = 0; ks < 8; ++ks) {
        int cur = ks & 1;
        if (ks < 7) stage(ks + 1, cur ^ 1);
        short8 af[4], bf_[4];
        #pragma unroll
        for (int rf = 0; rf < 4; rf++)
            af[rf] = *(const short8*)&Al[cur][(rf * 16 + l15) * KPAD + lg * 8];
        #pragma unroll
        for (int cf = 0; cf < 4; cf++)
            bf_[cf] = *(const short8*)&Bl[cur][(w * 64 + cf * 16 + l15) * KPAD + lg * 8];
        #pragma unroll
        for (int rf = 0; rf < 4; rf++)
            #pragma unroll
            for (int cf = 0; cf < 4; cf++)
                acc[rf][cf] = __builtin_amdgcn_mfma_f32_16x16x32_bf16(af[rf], bf_[cf], acc[rf][cf], 0, 0, 0);
        __syncthreads();
    }

    // epilogue: e-partials over this wave's 64 cols
    float esum[4][4];
    #pragma unroll
    for (int rf = 0; rf < 4; rf++)
        #pragma unroll
        for (int r = 0; r < 4; r++) esum[rf][r] = 0.f;

    #pragma unroll
    for (int cf = 0; cf < 4; cf++) {
        int col = w * 64 + cf * 16 + l15;
        float wsv = Wsc[col];
        float hd = hid[b * 256 + col];
        #pragma unroll
        for (int rf = 0; rf < 4; rf++)
            #pragma unroll
            for (int r = 0; r < 4; r++)
                esum[rf][r] += wsv * tanh_fast(acc[rf][cf][r] + hd);
    }
    #pragma unroll
    for (int rf = 0; rf < 4; rf++)
        #pragma unroll
        for (int r = 0; r < 4; r++) {
            float s = esum[rf][r];
            s += __shfl_xor(s, 1); s += __shfl_xor(s, 2);
            s += __shfl_xor(s, 4); s += __shfl_xor(s, 8);
            esum[rf][r] = s;
        }
    if (l15 == 0) {
        #pragma unroll
        for (int rf = 0; rf < 4; rf++)
            #pragma unroll
            for (int r = 0; r < 4; r++)
                eps[w][rf * 16 + lg * 4 + r] = esum[rf][r];
    }
    __syncthreads();
    if (tid < 64)
        e_out[bt0 + tid] = eps[0][tid] + eps[1][tid] + eps[2][tid] + eps[3][tid];
}

// ---------------- K2: softmax over T=512 per b ----------------
__global__ __launch_bounds__(256) void k_softmax(const float* __restrict__ e, float* __restrict__ alpha)
{
    int b = blockIdx.x, t = threadIdx.x;
    float v0 = e[b * 512 + t], v1 = e[b * 512 + 256 + t];
    float m = fmaxf(v0, v1);
    #pragma unroll
    for (int off = 32; off; off >>= 1) m = fmaxf(m, __shfl_xor(m, off));
    __shared__ float r1[4], r2[4];
    if ((t & 63) == 0) r1[t >> 6] = m;
    __syncthreads();
    m = fmaxf(fmaxf(r1[0], r1[1]), fmaxf(r1[2], r1[3]));
    float a0 = __expf(v0 - m), a1 = __expf(v1 - m);
    float s = a0 + a1;
    #pragma unroll
    for (int off = 32; off; off >>= 1) s += __shfl_xor(s, off);
    if ((t & 63) == 0) r2[t >> 6] = s;
    __syncthreads();
    s = r2[0] + r2[1] + r2[2] + r2[3];
    float inv = 1.f / s;
    alpha[b * 512 + t] = a0 * inv;
    alpha[b * 512 + 256 + t] = a1 * inv;
}

// ---------------- K3: context partials ctx[c][b][d] ----------------
__global__ __launch_bounds__(256) void k_context(
    const float* __restrict__ BH, const float* __restrict__ alpha, float* __restrict__ ctx)
{
    __shared__ float al[64];
    int bid = blockIdx.x;
    int b = bid >> 3, c = bid & 7;
    int tid = threadIdx.x;
    if (tid < 64) al[tid] = alpha[b * 512 + c * 64 + tid];
    __syncthreads();
    const float* bh = BH + ((size_t)(b * 512 + c * 64)) * 256 + tid;
    float acc = 0.f;
    #pragma unroll 8
    for (int t = 0; t < 64; t++) acc += al[t] * bh[(size_t)t * 256];
    ctx[(c * 256 + b) * 256 + tid] = acc;
}

// ---------------- K3b: assemble x = [context | onehots | prev_h | 0pad] as bf16 chunks ----------------
__global__ __launch_bounds__(256) void k_buildx(
    const float* __restrict__ ctx, const float* __restrict__ onehot,
    const float* __restrict__ prev_h, short* __restrict__ X)
{
    int idx = blockIdx.x * 256 + threadIdx.x;   // < 204800 = 20*256*40
    int kc = idx / (256 * KPAD);
    int rem = idx % (256 * KPAD);
    int bb = rem / KPAD, kk = rem % KPAD;
    float v = 0.f;
    if (kk < 32) {
        int k = kc * 32 + kk;
        if (k < 256) {
            #pragma unroll
            for (int c = 0; c < 8; c++) v += ctx[(c * 256 + bb) * 256 + k];
        } else if (k < 352) v = onehot[bb * 96 + (k - 256)];
        else if (k < 608)   v = prev_h[bb * 256 + (k - 352)];
    }
    X[idx] = (short)f2bfu(v);
}

// ---------------- K4: gates GEMM 256x1024, K=640 (bf16 MFMA), + biases ----------------
__global__ __launch_bounds__(256) void k_gates(
    const short* __restrict__ X, const short* __restrict__ Wcat,
    const float* __restrict__ b_ih, const float* __restrict__ b_hh,
    float* __restrict__ gates)
{
    __shared__ short Al[64 * KPAD];
    __shared__ short Bl[256 * KPAD];
    const int tid = threadIdx.x;
    const int lane = tid & 63;
    const int w = tid >> 6;
    const int l15 = lane & 15, lg = lane >> 4;
    const int rb = blockIdx.x * 64, cb = blockIdx.y * 256;

    f32x4 acc[4][4];
    #pragma unroll
    for (int i = 0; i < 4; i++)
        #pragma unroll
        for (int j = 0; j < 4; j++) acc[i][j] = (f32x4){0.f, 0.f, 0.f, 0.f};

    for (int kc = 0; kc < 20; ++kc) {
        __syncthreads();
        for (int u = tid; u < 1600; u += 256) {   // 1280 B-units + 320 A-units (16B each)
            if (u < 1280) {
                int n = u / 5, i = u % 5;
                ((int4*)&Bl[n * KPAD])[i] = ((const int4*)(Wcat + ((size_t)kc * 1024 + cb + n) * KPAD))[i];
            } else {
                int u2 = u - 1280;
                int r = u2 / 5, i = u2 % 5;
                ((int4*)&Al[r * KPAD])[i] = ((const int4*)(X + ((size_t)kc * 256 + rb + r) * KPAD))[i];
            }
        }
        __syncthreads();
        short8 af[4], bf_[4];
        #pragma unroll
        for (int rf = 0; rf < 4; rf++)
            af[rf] = *(const short8*)&Al[(rf * 16 + l15) * KPAD + lg * 8];
        #pragma unroll
        for (int cf = 0; cf < 4; cf++)
            bf_[cf] = *(const short8*)&Bl[(w * 64 + cf * 16 + l15) * KPAD + lg * 8];
        #pragma unroll
        for (int rf = 0; rf < 4; rf++)
            #pragma unroll
            for (int cf = 0; cf < 4; cf++)
                acc[rf][cf] = __builtin_amdgcn_mfma_f32_16x16x32_bf16(af[rf], bf_[cf], acc[rf][cf], 0, 0, 0);
    }
    #pragma unroll
    for (int cf = 0; cf < 4; cf++) {
        int col = cb + w * 64 + cf * 16 + l15;
        float bias = b_ih[col] + b_hh[col];
        #pragma unroll
        for (int rf = 0; rf < 4; rf++)
            #pragma unroll
            for (int r = 0; r < 4; r++) {
                int row = rb + rf * 16 + lg * 4 + r;
                gates[row * 1024 + col] = acc[rf][cf][r] + bias;
            }
    }
}

// ---------------- K5: LSTM elementwise ----------------
__global__ __launch_bounds__(256) void k_lstm(
    const float* __restrict__ gates, const float* __restrict__ prev_c, float* __restrict__ out)
{
    int idx = blockIdx.x * 256 + threadIdx.x;   // < 65536
    int b = idx >> 8, h = idx & 255;
    const float* g = gates + b * 1024;
    float gi = g[h], gf = g[256 + h], gg = g[512 + h], go = g[768 + h];
    float c = sigmoid_fast(gf) * prev_c[idx] + sigmoid_fast(gi) * tanh_fast(gg);
    float hn = sigmoid_fast(go) * tanh_fast(c);
    out[idx] = hn;
    out[65536 + idx] = c;
}

extern "C" void kernel_launch(void* const* d_in, const int* in_sizes, int n_in,
                              void* d_out, int out_size, void* d_ws, size_t ws_size,
                              hipStream_t stream) {
    (void)in_sizes; (void)n_in; (void)out_size; (void)ws_size;
    const float* prev_h  = (const float*)d_in[0];
    const float* prev_c  = (const float*)d_in[1];
    const float* batch_H = (const float*)d_in[2];
    const float* onehot  = (const float*)d_in[3];
    const float* W_i2h   = (const float*)d_in[4];
    const float* W_h2h   = (const float*)d_in[5];
    const float* b_h2h   = (const float*)d_in[6];
    const float* W_score = (const float*)d_in[7];
    const float* W_ih    = (const float*)d_in[8];
    const float* W_hh    = (const float*)d_in[9];
    const float* b_ih    = (const float*)d_in[10];
    const float* b_hh    = (const float*)d_in[11];

    char* ws = (char*)d_ws;
    float* hid   = (float*)(ws + WS_HID);
    float* e     = (float*)(ws + WS_E);
    float* ctx   = (float*)(ws + WS_CTX);
    float* gates = (float*)(ws + WS_GATES);
    short* Wbf   = (short*)(ws + WS_WBF);
    short* Wcat  = (short*)(ws + WS_WCAT);
    short* X     = (short*)(ws + WS_X);

    float* out = (float*)d_out;
    float* alpha = out + 131072;            // h:[0,65536) c:[65536,131072) alpha:[131072,262144)

    hipLaunchKernelGGL(k_prep,    dim3(3776),   dim3(256), 0, stream,
                       prev_h, W_i2h, W_h2h, b_h2h, W_ih, W_hh, hid, Wbf, Wcat);
    hipLaunchKernelGGL(k_escore,  dim3(2048),   dim3(256), 0, stream,
                       batch_H, Wbf, hid, W_score, e);
    hipLaunchKernelGGL(k_softmax, dim3(256),    dim3(256), 0, stream, e, alpha);
    hipLaunchKernelGGL(k_context, dim3(2048),   dim3(256), 0, stream, batch_H, alpha, ctx);
    hipLaunchKernelGGL(k_buildx,  dim3(800),    dim3(256), 0, stream, ctx, onehot, prev_h, X);
    hipLaunchKernelGGL(k_gates,   dim3(4, 4),   dim3(256), 0, stream, X, Wcat, b_ih, b_hh, gates);
    hipLaunchKernelGGL(k_lstm,    dim3(256),    dim3(256), 0, stream, gates, prev_c, out);
}

// Round 2
// 91.733 us; speedup vs baseline: 1.4702x; 1.4702x over previous
//
#include <hip/hip_runtime.h>

typedef __attribute__((ext_vector_type(8))) short short8;
typedef __attribute__((ext_vector_type(4))) float f32x4;

#define KPAD 40   // padded bf16 K-chunk row: 32 data + 8 pad (80B stride, 2-way-bank = free)

// workspace layout (bytes)
#define WS_HID    0u                 // 256*256 f32      = 262144
#define WS_E      262144u            // 131072 f32       = 524288
#define WS_CTX    786432u            // 256*256 f32      = 262144
#define WS_WBF    1048576u           // 8*256*40 bf16    = 163840
#define WS_WCAT   1212416u           // 19*1024*40 bf16  = 1556480  (ends 2768896)

__device__ __forceinline__ unsigned f2bfu(float f) {
    union { float f; unsigned u; } v; v.f = f;
    return (v.u + 0x7FFFu + ((v.u >> 16) & 1u)) >> 16;   // RNE
}
__device__ __forceinline__ float tanh_fast(float x) {
    float e2 = __expf(2.f * x);
    return 1.f - 2.f * __builtin_amdgcn_rcpf(e2 + 1.f);
}
__device__ __forceinline__ float sigmoid_fast(float x) {
    return __builtin_amdgcn_rcpf(1.f + __expf(-x));
}

// ---------------- K0: hid GEMV + weight bf16 pre-chunking ----------------
// Wcat is gate-interleaved: output row n' = h*4+g  <->  original row g*256+h,
// so a 64-col GEMM tile owns all 4 gates for 16 h's (enables in-block LSTM).
__global__ __launch_bounds__(256) void k_prep(
    const float* __restrict__ prev_h, const float* __restrict__ W_i2h,
    const float* __restrict__ W_h2h, const float* __restrict__ b_h2h,
    const float* __restrict__ W_ih,  const float* __restrict__ W_hh,
    float* __restrict__ hid, short* __restrict__ Wbf, short* __restrict__ Wcat)
{
    int bid = blockIdx.x, tid = threadIdx.x;
    if (bid < 256) {                       // hid[b][h] = prev_h[b]·W_h2h[h] + b_h2h[h]
        __shared__ float ph[256];
        ph[tid] = prev_h[bid * 256 + tid];
        __syncthreads();
        float acc = b_h2h[tid];
        const float4* w = (const float4*)(W_h2h + tid * 256);
        #pragma unroll 8
        for (int k4 = 0; k4 < 64; ++k4) {
            float4 ww = w[k4];
            acc += ww.x * ph[k4*4+0] + ww.y * ph[k4*4+1] + ww.z * ph[k4*4+2] + ww.w * ph[k4*4+3];
        }
        hid[bid * 256 + tid] = acc;
    } else if (bid < 576) {                // W_i2h -> bf16 chunks [8][256][40]
        int idx = (bid - 256) * 256 + tid;         // < 81920
        int kc = idx / (256 * KPAD);
        int rem = idx % (256 * KPAD);
        int n = rem / KPAD, kk = rem % KPAD;
        float v = (kk < 32) ? W_i2h[n * 256 + kc * 32 + kk] : 0.f;
        Wbf[idx] = (short)f2bfu(v);
    } else {                               // [W_ih | W_hh] -> bf16 chunks [19][1024][40], gate-interleaved
        int idx = (bid - 576) * 256 + tid;         // < 778240
        int kc = idx / (1024 * KPAD);
        int rem = idx % (1024 * KPAD);
        int np = rem / KPAD, kk = rem % KPAD;
        int h = np >> 2, g = np & 3;
        float v = 0.f;
        if (kk < 32) {
            int k = kc * 32 + kk;                  // < 608 always (kc<=18, kk<32)
            if (k < 352) v = W_ih[(g * 256 + h) * 352 + k];
            else         v = W_hh[(g * 256 + h) * 256 + (k - 352)];
        }
        Wcat[idx] = (short)f2bfu(v);
    }
}

// ---------------- K1: e[bt] = sum_h Wsc[h]*tanh(BH·W_i2h^T + hid) ----------------
// block: 64 bt-rows x 256 h-cols, 4 waves (N-split 4x64), K=256 in 8 steps of 32
__global__ __launch_bounds__(256, 3) void k_escore(
    const float* __restrict__ BH, const short* __restrict__ Wbf,
    const float* __restrict__ hid, const float* __restrict__ Wsc,
    float* __restrict__ e_out)
{
    __shared__ short Al[2][64 * KPAD];
    __shared__ short Bl[2][256 * KPAD];
    __shared__ float eps[4][64];

    const int tid = threadIdx.x;
    const int lane = tid & 63;
    const int w = tid >> 6;
    const int l15 = lane & 15, lg = lane >> 4;
    const int bt0 = blockIdx.x * 64;
    const int b = bt0 >> 9;

    const int arow = tid >> 2, akg = tid & 3;
    const float* asrc = BH + (size_t)(bt0 + arow) * 256 + akg * 8;

    f32x4 acc[4][4];
    #pragma unroll
    for (int i = 0; i < 4; i++)
        #pragma unroll
        for (int j = 0; j < 4; j++) acc[i][j] = (f32x4){0.f, 0.f, 0.f, 0.f};

    auto stage = [&](int kc, int bu) {
        // A: 64x32 fp32 -> bf16 (each thread: 8 floats of one row)
        float4 x0 = *(const float4*)(asrc + kc * 32);
        float4 x1 = *(const float4*)(asrc + kc * 32 + 4);
        int4 p;
        p.x = (int)((f2bfu(x0.y) << 16) | f2bfu(x0.x));
        p.y = (int)((f2bfu(x0.w) << 16) | f2bfu(x0.z));
        p.z = (int)((f2bfu(x1.y) << 16) | f2bfu(x1.x));
        p.w = (int)((f2bfu(x1.w) << 16) | f2bfu(x1.z));
        *(int4*)&Al[bu][arow * KPAD + akg * 8] = p;
        // B: pre-chunked bf16 [kc][256][40]; thread = one n-row (80B = 5x int4)
        const int4* bs = (const int4*)(Wbf + (size_t)(kc * 256 + tid) * KPAD);
        int4* bd = (int4*)&Bl[bu][tid * KPAD];
        #pragma unroll
        for (int i = 0; i < 5; i++) bd[i] = bs[i];
    };

    stage(0, 0);
    __syncthreads();

    for (int ks = 0; ks < 8; ++ks) {
        int cur = ks & 1;
        short8 af[4], bf_[4];
        #pragma unroll
        for (int rf = 0; rf < 4; rf++)
            af[rf] = *(const short8*)&Al[cur][(rf * 16 + l15) * KPAD + lg * 8];
        #pragma unroll
        for (int cf = 0; cf < 4; cf++)
            bf_[cf] = *(const short8*)&Bl[cur][(w * 64 + cf * 16 + l15) * KPAD + lg * 8];
        if (ks < 7) stage(ks + 1, cur ^ 1);
        #pragma unroll
        for (int rf = 0; rf < 4; rf++)
            #pragma unroll
            for (int cf = 0; cf < 4; cf++)
                acc[rf][cf] = __builtin_amdgcn_mfma_f32_16x16x32_bf16(af[rf], bf_[cf], acc[rf][cf], 0, 0, 0);
        __syncthreads();
    }

    // epilogue: e-partials over this wave's 64 cols
    float esum[4][4];
    #pragma unroll
    for (int rf = 0; rf < 4; rf++)
        #pragma unroll
        for (int r = 0; r < 4; r++) esum[rf][r] = 0.f;

    #pragma unroll
    for (int cf = 0; cf < 4; cf++) {
        int col = w * 64 + cf * 16 + l15;
        float wsv = Wsc[col];
        float hd = hid[b * 256 + col];
        #pragma unroll
        for (int rf = 0; rf < 4; rf++)
            #pragma unroll
            for (int r = 0; r < 4; r++)
                esum[rf][r] += wsv * tanh_fast(acc[rf][cf][r] + hd);
    }
    #pragma unroll
    for (int rf = 0; rf < 4; rf++)
        #pragma unroll
        for (int r = 0; r < 4; r++) {
            float s = esum[rf][r];
            s += __shfl_xor(s, 1); s += __shfl_xor(s, 2);
            s += __shfl_xor(s, 4); s += __shfl_xor(s, 8);
            esum[rf][r] = s;
        }
    if (l15 == 0) {
        #pragma unroll
        for (int rf = 0; rf < 4; rf++)
            #pragma unroll
            for (int r = 0; r < 4; r++)
                eps[w][rf * 16 + lg * 4 + r] = esum[rf][r];
    }
    __syncthreads();
    if (tid < 64)
        e_out[bt0 + tid] = eps[0][tid] + eps[1][tid] + eps[2][tid] + eps[3][tid];
}

// ---------------- K2: fused softmax + context; one block per batch b ----------------
__global__ __launch_bounds__(256) void k_smctx(
    const float* __restrict__ e, const float* __restrict__ BH,
    float* __restrict__ alpha_out, float* __restrict__ ctx)
{
    __shared__ float al[512];
    __shared__ float r1[4], r2[4];
    int b = blockIdx.x, t = threadIdx.x;
    float v0 = e[b * 512 + t], v1 = e[b * 512 + 256 + t];
    float m = fmaxf(v0, v1);
    #pragma unroll
    for (int off = 32; off; off >>= 1) m = fmaxf(m, __shfl_xor(m, off));
    if ((t & 63) == 0) r1[t >> 6] = m;
    __syncthreads();
    m = fmaxf(fmaxf(r1[0], r1[1]), fmaxf(r1[2], r1[3]));
    float a0 = __expf(v0 - m), a1 = __expf(v1 - m);
    float s = a0 + a1;
    #pragma unroll
    for (int off = 32; off; off >>= 1) s += __shfl_xor(s, off);
    if ((t & 63) == 0) r2[t >> 6] = s;
    __syncthreads();
    s = r2[0] + r2[1] + r2[2] + r2[3];
    float inv = 1.f / s;
    a0 *= inv; a1 *= inv;
    alpha_out[b * 512 + t] = a0;
    alpha_out[b * 512 + 256 + t] = a1;
    al[t] = a0; al[256 + t] = a1;
    __syncthreads();
    // context: thread t owns column d = t; stream 512 rows of this b's slice
    const float* bh = BH + (size_t)b * 512 * 256 + t;
    float acc = 0.f;
    #pragma unroll 16
    for (int tt = 0; tt < 512; ++tt) acc += al[tt] * bh[(size_t)tt * 256];
    ctx[b * 256 + t] = acc;
}

// ---------------- K3: gates GEMM (256x1024, K=608=19x32) fused with LSTM ----------------
// grid (4 row-blocks, 16 col-blocks); block tile 64 rows x 64 gate-interleaved cols
// (= all 4 gates of 16 h's). A assembled in-block from [ctx|onehot|prev_h].
__global__ __launch_bounds__(256) void k_gates_lstm(
    const float* __restrict__ ctx, const float* __restrict__ onehot,
    const float* __restrict__ prev_h, const short* __restrict__ Wcat,
    const float* __restrict__ b_ih, const float* __restrict__ b_hh,
    const float* __restrict__ prev_c, float* __restrict__ out)
{
    __shared__ char smem[20800];
    short* AlB = (short*)smem;            // [2][64*KPAD]
    short* BlB = (short*)smem + 5120;     // [2][64*KPAD]
    const int tid = threadIdx.x;
    const int lane = tid & 63;
    const int w = tid >> 6;
    const int l15 = lane & 15, lg = lane >> 4;
    const int rb = blockIdx.x * 64;       // row base (batch)
    const int hb = blockIdx.y;            // col-block: n' in [hb*64, hb*64+64)

    f32x4 acc[4];
    #pragma unroll
    for (int j = 0; j < 4; j++) acc[j] = (f32x4){0.f, 0.f, 0.f, 0.f};

    const int arow = tid >> 2, akg = tid & 3;
    const int rg = rb + arow;

    auto stageAB = [&](int kc, int bu) {
        // A: 64x32, assembled from ctx / onehot / prev_h, fp32 -> bf16
        int k0 = kc * 32 + akg * 8;
        const float4* p;
        if (k0 < 256)      p = (const float4*)(ctx    + rg * 256 + k0);
        else if (k0 < 352) p = (const float4*)(onehot + rg * 96  + (k0 - 256));
        else               p = (const float4*)(prev_h + rg * 256 + (k0 - 352));
        float4 x0 = p[0], x1 = p[1];
        int4 q;
        q.x = (int)((f2bfu(x0.y) << 16) | f2bfu(x0.x));
        q.y = (int)((f2bfu(x0.w) << 16) | f2bfu(x0.z));
        q.z = (int)((f2bfu(x1.y) << 16) | f2bfu(x1.x));
        q.w = (int)((f2bfu(x1.w) << 16) | f2bfu(x1.z));
        *(int4*)&AlB[bu * 2560 + arow * KPAD + akg * 8] = q;
        // B: 64 n'-rows x 40 from Wcat chunk kc (320 x 16B units)
        {
            int u = tid;                          // units 0..255
            int n = u / 5, i = u % 5;
            ((int4*)&BlB[bu * 2560 + n * KPAD])[i] =
                ((const int4*)(Wcat + ((size_t)kc * 1024 + hb * 64 + n) * KPAD))[i];
        }
        if (tid < 64) {                           // units 256..319
            int u = tid + 256;
            int n = u / 5, i = u % 5;
            ((int4*)&BlB[bu * 2560 + n * KPAD])[i] =
                ((const int4*)(Wcat + ((size_t)kc * 1024 + hb * 64 + n) * KPAD))[i];
        }
    };

    stageAB(0, 0);
    __syncthreads();

    for (int kc = 0; kc < 19; ++kc) {
        int cur = kc & 1;
        short8 af = *(const short8*)&AlB[cur * 2560 + (w * 16 + l15) * KPAD + lg * 8];
        short8 bf_[4];
        #pragma unroll
        for (int cf = 0; cf < 4; cf++)
            bf_[cf] = *(const short8*)&BlB[cur * 2560 + (cf * 16 + l15) * KPAD + lg * 8];
        if (kc < 18) stageAB(kc + 1, cur ^ 1);
        #pragma unroll
        for (int cf = 0; cf < 4; cf++)
            acc[cf] = __builtin_amdgcn_mfma_f32_16x16x32_bf16(af, bf_[cf], acc[cf], 0, 0, 0);
        __syncthreads();
    }

    // gates tile -> LDS (reuse staging memory), add biases
    float* Gt = (float*)smem;                    // [64][65]
    #pragma unroll
    for (int cf = 0; cf < 4; cf++) {
        int col = cf * 16 + l15;
        int np = hb * 64 + col;
        int hg = np >> 2, g = np & 3;
        float bias = b_ih[g * 256 + hg] + b_hh[g * 256 + hg];
        #pragma unroll
        for (int r = 0; r < 4; r++)
            Gt[(w * 16 + lg * 4 + r) * 65 + col] = acc[cf][r] + bias;
    }
    __syncthreads();

    // LSTM elementwise: 64 rows x 16 h per block
    #pragma unroll
    for (int it = 0; it < 4; ++it) {
        int elem = it * 256 + tid;               // < 1024
        int row = elem >> 4, hl = elem & 15;
        float gi = Gt[row * 65 + hl * 4 + 0];
        float gf = Gt[row * 65 + hl * 4 + 1];
        float gg = Gt[row * 65 + hl * 4 + 2];
        float go = Gt[row * 65 + hl * 4 + 3];
        int bg = rb + row, hglob = hb * 16 + hl;
        float c = sigmoid_fast(gf) * prev_c[bg * 256 + hglob] + sigmoid_fast(gi) * tanh_fast(gg);
        out[bg * 256 + hglob] = sigmoid_fast(go) * tanh_fast(c);
        out[65536 + bg * 256 + hglob] = c;
    }
}

extern "C" void kernel_launch(void* const* d_in, const int* in_sizes, int n_in,
                              void* d_out, int out_size, void* d_ws, size_t ws_size,
                              hipStream_t stream) {
    (void)in_sizes; (void)n_in; (void)out_size; (void)ws_size;
    const float* prev_h  = (const float*)d_in[0];
    const float* prev_c  = (const float*)d_in[1];
    const float* batch_H = (const float*)d_in[2];
    const float* onehot  = (const float*)d_in[3];
    const float* W_i2h   = (const float*)d_in[4];
    const float* W_h2h   = (const float*)d_in[5];
    const float* b_h2h   = (const float*)d_in[6];
    const float* W_score = (const float*)d_in[7];
    const float* W_ih    = (const float*)d_in[8];
    const float* W_hh    = (const float*)d_in[9];
    const float* b_ih    = (const float*)d_in[10];
    const float* b_hh    = (const float*)d_in[11];

    char* ws = (char*)d_ws;
    float* hid   = (float*)(ws + WS_HID);
    float* e     = (float*)(ws + WS_E);
    float* ctx   = (float*)(ws + WS_CTX);
    short* Wbf   = (short*)(ws + WS_WBF);
    short* Wcat  = (short*)(ws + WS_WCAT);

    float* out = (float*)d_out;
    float* alpha = out + 131072;            // h:[0,64K) c:[64K,128K) alpha:[128K,256K) floats

    hipLaunchKernelGGL(k_prep,       dim3(3616),   dim3(256), 0, stream,
                       prev_h, W_i2h, W_h2h, b_h2h, W_ih, W_hh, hid, Wbf, Wcat);
    hipLaunchKernelGGL(k_escore,     dim3(2048),   dim3(256), 0, stream,
                       batch_H, Wbf, hid, W_score, e);
    hipLaunchKernelGGL(k_smctx,      dim3(256),    dim3(256), 0, stream,
                       e, batch_H, alpha, ctx);
    hipLaunchKernelGGL(k_gates_lstm, dim3(4, 16),  dim3(256), 0, stream,
                       ctx, onehot, prev_h, Wcat, b_ih, b_hh, prev_c, out);
}

// Round 3
// 79.329 us; speedup vs baseline: 1.7001x; 1.1564x over previous
//
#include <hip/hip_runtime.h>

typedef __attribute__((ext_vector_type(8))) short short8;
typedef __attribute__((ext_vector_type(4))) float f32x4;

#define KPAD 40   // padded bf16 K-chunk row: 32 data + 8 pad (80B stride, 2-way-bank = free)

// workspace layout (bytes)
#define WS_HID    0u                 // 256*256 f32      = 262144
#define WS_P      262144u            // 131072 f32 (unnormalized exp(e))
#define WS_Z      786432u            // 2048 f32
#define WS_CTX    794624u            // 256*256 f32
#define WS_CTXP   1056768u           // 8*256*256 f32 partials (ends 3153920)
#define WS_WBF    3153920u           // 8*256*40 bf16

__device__ __forceinline__ unsigned f2bfu(float f) {
    union { float f; unsigned u; } v; v.f = f;
    return (v.u + 0x7FFFu + ((v.u >> 16) & 1u)) >> 16;   // RNE
}
__device__ __forceinline__ float bf2f(short s) {
    union { float f; unsigned u; } v; v.u = ((unsigned)(unsigned short)s) << 16;
    return v.f;
}
__device__ __forceinline__ float tanh_fast(float x) {
    float e2 = __expf(2.f * x);
    return 1.f - 2.f * __builtin_amdgcn_rcpf(e2 + 1.f);
}
__device__ __forceinline__ float sigmoid_fast(float x) {
    return __builtin_amdgcn_rcpf(1.f + __expf(-x));
}
__device__ __forceinline__ int4 pack8(float4 x0, float4 x1) {
    int4 q;
    q.x = (int)((f2bfu(x0.y) << 16) | f2bfu(x0.x));
    q.y = (int)((f2bfu(x0.w) << 16) | f2bfu(x0.z));
    q.z = (int)((f2bfu(x1.y) << 16) | f2bfu(x1.x));
    q.w = (int)((f2bfu(x1.w) << 16) | f2bfu(x1.z));
    return q;
}

// ---------------- K0: hid GEMV + W_i2h bf16 pre-chunking ----------------
__global__ __launch_bounds__(256) void k_prep(
    const float* __restrict__ prev_h, const float* __restrict__ W_i2h,
    const float* __restrict__ W_h2h, const float* __restrict__ b_h2h,
    float* __restrict__ hid, short* __restrict__ Wbf)
{
    int bid = blockIdx.x, tid = threadIdx.x;
    if (bid < 256) {                       // hid[b][h] = prev_h[b]·W_h2h[h] + b_h2h[h]
        __shared__ float ph[256];
        ph[tid] = prev_h[bid * 256 + tid];
        __syncthreads();
        float acc = b_h2h[tid];
        const float4* w = (const float4*)(W_h2h + tid * 256);
        #pragma unroll 8
        for (int k4 = 0; k4 < 64; ++k4) {
            float4 ww = w[k4];
            acc += ww.x * ph[k4*4+0] + ww.y * ph[k4*4+1] + ww.z * ph[k4*4+2] + ww.w * ph[k4*4+3];
        }
        hid[bid * 256 + tid] = acc;
    } else {                               // W_i2h -> bf16 chunks [8][256][40]
        int idx = (bid - 256) * 256 + tid;         // < 81920
        int kc = idx / (256 * KPAD);
        int rem = idx % (256 * KPAD);
        int n = rem / KPAD, kk = rem % KPAD;
        float v = (kk < 32) ? W_i2h[n * 256 + kc * 32 + kk] : 0.f;
        Wbf[idx] = (short)f2bfu(v);
    }
}

// ---------------- K1: fused e-score + unnormalized softmax + context partial ----------------
// block: 64 bt-rows x 256 h-cols, 4 waves. A-tiles resident in LDS (8 chunks);
// B double-buffered. Epilogue: e -> p=exp(e) (no max needed: |e| <= ||Wsc||_1 ~ 10),
// then ctx partial GEMV from LDS A-tiles (batch_H read from HBM exactly once).
__global__ __launch_bounds__(256, 2) void k_escore_ctx(
    const float* __restrict__ BH, const short* __restrict__ Wbf,
    const float* __restrict__ hid, const float* __restrict__ Wsc,
    float* __restrict__ p_out, float* __restrict__ zbuf, float* __restrict__ ctxp)
{
    __shared__ char smem[81920];
    short* Al = (short*)smem;                   // [8][64][40] resident A chunks
    short* Bl = (short*)(smem + 40960);         // [2][256][40] double-buffered B
    float* eps = (float*)(smem + 40960);        // overlay (B dead after K-loop): [4][64]
    float* pl  = (float*)(smem + 41984);        // [64]
    float* r8  = (float*)(smem + 42240);        // [8][256]

    const int tid = threadIdx.x;
    const int lane = tid & 63;
    const int w = tid >> 6;
    const int l15 = lane & 15, lg = lane >> 4;
    const int bt0 = blockIdx.x * 64;
    const int b = bt0 >> 9;
    const int c = (bt0 >> 6) & 7;

    const int arow = tid >> 2, akg = tid & 3;
    const float* asrc = BH + (size_t)(bt0 + arow) * 256 + akg * 8;

    f32x4 acc[4][4];
    #pragma unroll
    for (int i = 0; i < 4; i++)
        #pragma unroll
        for (int j = 0; j < 4; j++) acc[i][j] = (f32x4){0.f, 0.f, 0.f, 0.f};

    auto stage = [&](int kc) {
        float4 x0 = *(const float4*)(asrc + kc * 32);
        float4 x1 = *(const float4*)(asrc + kc * 32 + 4);
        *(int4*)&Al[kc * 2560 + arow * KPAD + akg * 8] = pack8(x0, x1);
        const int4* bs = (const int4*)(Wbf + (size_t)(kc * 256 + tid) * KPAD);
        int4* bd = (int4*)&Bl[(kc & 1) * 10240 + tid * KPAD];
        #pragma unroll
        for (int i = 0; i < 5; i++) bd[i] = bs[i];
    };

    stage(0);
    __syncthreads();

    for (int ks = 0; ks < 8; ++ks) {
        short8 af[4], bf_[4];
        #pragma unroll
        for (int rf = 0; rf < 4; rf++)
            af[rf] = *(const short8*)&Al[ks * 2560 + (rf * 16 + l15) * KPAD + lg * 8];
        #pragma unroll
        for (int cf = 0; cf < 4; cf++)
            bf_[cf] = *(const short8*)&Bl[(ks & 1) * 10240 + (w * 64 + cf * 16 + l15) * KPAD + lg * 8];
        if (ks < 7) stage(ks + 1);
        #pragma unroll
        for (int rf = 0; rf < 4; rf++)
            #pragma unroll
            for (int cf = 0; cf < 4; cf++)
                acc[rf][cf] = __builtin_amdgcn_mfma_f32_16x16x32_bf16(af[rf], bf_[cf], acc[rf][cf], 0, 0, 0);
        __syncthreads();
    }

    // ---- epilogue: e partials over this wave's 64 cols ----
    float esum[4][4];
    #pragma unroll
    for (int rf = 0; rf < 4; rf++)
        #pragma unroll
        for (int r = 0; r < 4; r++) esum[rf][r] = 0.f;

    #pragma unroll
    for (int cf = 0; cf < 4; cf++) {
        int col = w * 64 + cf * 16 + l15;
        float wsv = Wsc[col];
        float hd = hid[b * 256 + col];
        #pragma unroll
        for (int rf = 0; rf < 4; rf++)
            #pragma unroll
            for (int r = 0; r < 4; r++)
                esum[rf][r] += wsv * tanh_fast(acc[rf][cf][r] + hd);
    }
    #pragma unroll
    for (int rf = 0; rf < 4; rf++)
        #pragma unroll
        for (int r = 0; r < 4; r++) {
            float s = esum[rf][r];
            s += __shfl_xor(s, 1); s += __shfl_xor(s, 2);
            s += __shfl_xor(s, 4); s += __shfl_xor(s, 8);
            esum[rf][r] = s;
        }
    if (l15 == 0) {
        #pragma unroll
        for (int rf = 0; rf < 4; rf++)
            #pragma unroll
            for (int r = 0; r < 4; r++)
                eps[w * 64 + rf * 16 + lg * 4 + r] = esum[rf][r];
    }
    __syncthreads();

    if (tid < 64) {
        float e = eps[tid] + eps[64 + tid] + eps[128 + tid] + eps[192 + tid];
        float p = __expf(e);            // |e| <= ||Wsc||_1 ~ 10.2 -> no overflow, softmax shift-invariant
        p_out[bt0 + tid] = p;
        pl[tid] = p;
        float z = p;
        z += __shfl_xor(z, 1); z += __shfl_xor(z, 2); z += __shfl_xor(z, 4);
        z += __shfl_xor(z, 8); z += __shfl_xor(z, 16); z += __shfl_xor(z, 32);
        if (tid == 0) zbuf[blockIdx.x] = z;
    }
    __syncthreads();

    // ---- context partial: ctxp[d] = sum_t pl[t] * A[t][d], A from resident LDS ----
    // mapping t = tt*8 + tg breaks the 80B-stride bank aliasing
    {
        int tg = tid & 7, dg = tid >> 3;
        int d0 = dg * 8;
        int kc = d0 >> 5, dd = d0 & 31;
        float a8[8] = {0.f,0.f,0.f,0.f,0.f,0.f,0.f,0.f};
        #pragma unroll
        for (int tt = 0; tt < 8; ++tt) {
            int t = tt * 8 + tg;
            short8 v = *(const short8*)&Al[kc * 2560 + t * KPAD + dd];
            float pv = pl[t];
            #pragma unroll
            for (int j = 0; j < 8; ++j) a8[j] += pv * bf2f(v[j]);
        }
        #pragma unroll
        for (int j = 0; j < 8; ++j) r8[tg * 256 + d0 + j] = a8[j];
    }
    __syncthreads();
    {
        float s = 0.f;
        #pragma unroll
        for (int g = 0; g < 8; ++g) s += r8[g * 256 + tid];
        ctxp[((size_t)(c * 256 + b)) * 256 + tid] = s;
    }
}

// ---------------- K2: finalize alpha + ctx ----------------
__global__ __launch_bounds__(256) void k_finalize(
    const float* __restrict__ p, const float* __restrict__ zbuf,
    const float* __restrict__ ctxp, float* __restrict__ alpha, float* __restrict__ ctx)
{
    int b = blockIdx.x, t = threadIdx.x;
    float Z = 0.f;
    #pragma unroll
    for (int cc = 0; cc < 8; ++cc) Z += zbuf[b * 8 + cc];
    float inv = 1.f / Z;
    alpha[b * 512 + t] = p[b * 512 + t] * inv;
    alpha[b * 512 + 256 + t] = p[b * 512 + 256 + t] * inv;
    float s = 0.f;
    #pragma unroll
    for (int cc = 0; cc < 8; ++cc) s += ctxp[((size_t)(cc * 256 + b)) * 256 + t];
    ctx[b * 256 + t] = s * inv;
}

// ---------------- K3: gates GEMM (256x1024, K=608=19x32) fused with LSTM ----------------
// grid (4,16); block tile 64 rows x 64 gate-interleaved cols (n' = h*4+g).
// A assembled from [ctx|onehot|prev_h]; B staged fp32->bf16 directly from W_ih/W_hh.
__global__ __launch_bounds__(256) void k_gates_lstm(
    const float* __restrict__ ctx, const float* __restrict__ onehot,
    const float* __restrict__ prev_h, const float* __restrict__ W_ih,
    const float* __restrict__ W_hh, const float* __restrict__ b_ih,
    const float* __restrict__ b_hh, const float* __restrict__ prev_c,
    float* __restrict__ out)
{
    __shared__ char smem[20800];
    short* AlB = (short*)smem;            // [2][64*KPAD]
    short* BlB = (short*)smem + 5120;     // [2][64*KPAD]
    const int tid = threadIdx.x;
    const int lane = tid & 63;
    const int w = tid >> 6;
    const int l15 = lane & 15, lg = lane >> 4;
    const int rb = blockIdx.x * 64;       // row base (batch)
    const int hb = blockIdx.y;            // col-block: n' in [hb*64, hb*64+64)

    f32x4 acc[4];
    #pragma unroll
    for (int j = 0; j < 4; j++) acc[j] = (f32x4){0.f, 0.f, 0.f, 0.f};

    const int arow = tid >> 2, akg = tid & 3;
    const int rg = rb + arow;
    // B-row assignment: thread -> (n, quarter)
    const int bn = tid >> 2, bq = tid & 3;
    const int np_ = hb * 64 + bn, hh_ = np_ >> 2, gg_ = np_ & 3;
    const float* wih_row = W_ih + (size_t)(gg_ * 256 + hh_) * 352;
    const float* whh_row = W_hh + (size_t)(gg_ * 256 + hh_) * 256;

    auto stageAB = [&](int kc, int bu) {
        // A: 64x32, assembled from ctx / onehot / prev_h, fp32 -> bf16
        int k0 = kc * 32 + akg * 8;
        const float4* pa;
        if (k0 < 256)      pa = (const float4*)(ctx    + rg * 256 + k0);
        else if (k0 < 352) pa = (const float4*)(onehot + rg * 96  + (k0 - 256));
        else               pa = (const float4*)(prev_h + rg * 256 + (k0 - 352));
        float4 x0 = pa[0], x1 = pa[1];
        *(int4*)&AlB[bu * 2560 + arow * KPAD + akg * 8] = pack8(x0, x1);
        // B: 64 n'-rows x 32 k, read fp32 weights directly
        int kb = kc * 32 + bq * 8;
        const float* pb = (kb < 352) ? (wih_row + kb) : (whh_row + (kb - 352));
        float4 y0 = *(const float4*)pb, y1 = *(const float4*)(pb + 4);
        *(int4*)&BlB[bu * 2560 + bn * KPAD + bq * 8] = pack8(y0, y1);
    };

    stageAB(0, 0);
    __syncthreads();

    for (int kc = 0; kc < 19; ++kc) {
        int cur = kc & 1;
        short8 af = *(const short8*)&AlB[cur * 2560 + (w * 16 + l15) * KPAD + lg * 8];
        short8 bf_[4];
        #pragma unroll
        for (int cf = 0; cf < 4; cf++)
            bf_[cf] = *(const short8*)&BlB[cur * 2560 + (cf * 16 + l15) * KPAD + lg * 8];
        if (kc < 18) stageAB(kc + 1, cur ^ 1);
        #pragma unroll
        for (int cf = 0; cf < 4; cf++)
            acc[cf] = __builtin_amdgcn_mfma_f32_16x16x32_bf16(af, bf_[cf], acc[cf], 0, 0, 0);
        __syncthreads();
    }

    // gates tile -> LDS (reuse staging memory), add biases
    float* Gt = (float*)smem;                    // [64][65]
    #pragma unroll
    for (int cf = 0; cf < 4; cf++) {
        int col = cf * 16 + l15;
        int np = hb * 64 + col;
        int hg = np >> 2, g = np & 3;
        float bias = b_ih[g * 256 + hg] + b_hh[g * 256 + hg];
        #pragma unroll
        for (int r = 0; r < 4; r++)
            Gt[(w * 16 + lg * 4 + r) * 65 + col] = acc[cf][r] + bias;
    }
    __syncthreads();

    // LSTM elementwise: 64 rows x 16 h per block
    #pragma unroll
    for (int it = 0; it < 4; ++it) {
        int elem = it * 256 + tid;               // < 1024
        int row = elem >> 4, hl = elem & 15;
        float gi = Gt[row * 65 + hl * 4 + 0];
        float gf = Gt[row * 65 + hl * 4 + 1];
        float gg = Gt[row * 65 + hl * 4 + 2];
        float go = Gt[row * 65 + hl * 4 + 3];
        int bg = rb + row, hglob = hb * 16 + hl;
        float cv = sigmoid_fast(gf) * prev_c[bg * 256 + hglob] + sigmoid_fast(gi) * tanh_fast(gg);
        out[bg * 256 + hglob] = sigmoid_fast(go) * tanh_fast(cv);
        out[65536 + bg * 256 + hglob] = cv;
    }
}

extern "C" void kernel_launch(void* const* d_in, const int* in_sizes, int n_in,
                              void* d_out, int out_size, void* d_ws, size_t ws_size,
                              hipStream_t stream) {
    (void)in_sizes; (void)n_in; (void)out_size; (void)ws_size;
    const float* prev_h  = (const float*)d_in[0];
    const float* prev_c  = (const float*)d_in[1];
    const float* batch_H = (const float*)d_in[2];
    const float* onehot  = (const float*)d_in[3];
    const float* W_i2h   = (const float*)d_in[4];
    const float* W_h2h   = (const float*)d_in[5];
    const float* b_h2h   = (const float*)d_in[6];
    const float* W_score = (const float*)d_in[7];
    const float* W_ih    = (const float*)d_in[8];
    const float* W_hh    = (const float*)d_in[9];
    const float* b_ih    = (const float*)d_in[10];
    const float* b_hh    = (const float*)d_in[11];

    char* ws = (char*)d_ws;
    float* hid   = (float*)(ws + WS_HID);
    float* p     = (float*)(ws + WS_P);
    float* zbuf  = (float*)(ws + WS_Z);
    float* ctx   = (float*)(ws + WS_CTX);
    float* ctxp  = (float*)(ws + WS_CTXP);
    short* Wbf   = (short*)(ws + WS_WBF);

    float* out = (float*)d_out;
    float* alpha = out + 131072;            // h:[0,64K) c:[64K,128K) alpha:[128K,256K) floats

    hipLaunchKernelGGL(k_prep,       dim3(576),    dim3(256), 0, stream,
                       prev_h, W_i2h, W_h2h, b_h2h, hid, Wbf);
    hipLaunchKernelGGL(k_escore_ctx, dim3(2048),   dim3(256), 0, stream,
                       batch_H, Wbf, hid, W_score, p, zbuf, ctxp);
    hipLaunchKernelGGL(k_finalize,   dim3(256),    dim3(256), 0, stream,
                       p, zbuf, ctxp, alpha, ctx);
    hipLaunchKernelGGL(k_gates_lstm, dim3(4, 16),  dim3(256), 0, stream,
                       ctx, onehot, prev_h, W_ih, W_hh, b_ih, b_hh, prev_c, out);
}